// Round 8
// baseline (380.984 us; speedup 1.0000x reference)
//
#include <hip/hip_runtime.h>
#include <hip/hip_bf16.h>

// GraphSAGE net on MI355X — linearity-restructured + fused gather-GEMMs.
//   G1 = x @ [Wl1;Wr1;Ws].T      (fp32 A direct-to-register, NC=384)
//   G2 = (mean_nbr0(G1L)+G1M+bl1) @ [Wl2;Wr2].T    <- agg fused into A-load
//   out = relu((mean_nbr1(G2L)+G2R+G1R+bl2+bs)@W1.T+b1) @ W2.T + b2
//   h1/h3 never touch memory (r7: each was a 25.6MB round-trip + a launch).
// Streaming GEMM (r6 lesson): W staged ONCE frag-swizzled in LDS, zero barriers
// in the tile loop, A-frags built in registers.
// CSR build = zero-global-atomic partitioned counting sort (r3: same-address
// device atomics ~85ns; r4: spread device atomics ~32B fabric RMW each).

#define DD 128
#define SB 8               // 256 nodes per bucket
#define CH 8192            // edges per partition chunk (168B bucket runs in scatter)
typedef unsigned short u16;
typedef __attribute__((ext_vector_type(8))) short short8;
typedef __attribute__((ext_vector_type(4))) float f32x4;

__device__ inline u16 f2bf(float f) {
    __hip_bfloat16 h = __float2bfloat16(f);
    u16 u;
    __builtin_memcpy(&u, &h, 2);
    return u;
}
__device__ inline unsigned pack2(float lo, float hi) {
    return (unsigned)f2bf(lo) | ((unsigned)f2bf(hi) << 16);
}
__device__ inline float bf_lo(unsigned u) { union { unsigned x; float f; } c; c.x = u << 16; return c.f; }
__device__ inline float bf_hi(unsigned u) { union { unsigned x; float f; } c; c.x = u & 0xffff0000u; return c.f; }

// ---------------- weight cast fp32 -> bf16 (concat slots) ----------------
struct CastJobs {
    const float4* src[6];
    uint2* dst[6];
    int qstart[7];
};
__global__ __launch_bounds__(256) void cast_kernel(CastJobs jb) {
    int q = blockIdx.x * 256 + threadIdx.x;
    if (q >= jb.qstart[6]) return;
    int i = 0;
#pragma unroll
    for (int k = 1; k < 6; ++k) if (q >= jb.qstart[k]) i = k;
    int local = q - jb.qstart[i];
    float4 v = jb.src[i][local];
    jb.dst[i][local] = make_uint2(pack2(v.x, v.y), pack2(v.z, v.w));
}

// ---------------- CSR build ----------------
// hist1: per-(bucket,partition) counts via LDS histogram. grid (P, 2).
__global__ __launch_bounds__(256) void hist1_kernel(const int* __restrict__ dst0, int* __restrict__ h0,
                                                    const int* __restrict__ dst1, int* __restrict__ h1,
                                                    int e0, int e1, int nb, int P) {
    int arr = blockIdx.y;
    const int* dst = arr ? dst1 : dst0;
    int* hist = arr ? h1 : h0;
    int e = arr ? e1 : e0;
    __shared__ int h[256];
    int t = threadIdx.x;
    h[t] = 0;
    __syncthreads();
    int base = blockIdx.x * CH;
    int hi = min(base + CH, e);
    for (int i = base + t; i < hi; i += 256) atomicAdd(&h[dst[i] >> SB], 1);
    __syncthreads();
    if (t < nb) hist[t * P + blockIdx.x] = h[t];   // [bucket][partition]
}

// rowsum: bucket totals = sum_p hist1[b][p]. grid (nb, 2).
__global__ __launch_bounds__(256) void rowsum_kernel(const int* __restrict__ h0, int* __restrict__ bs0,
                                                     const int* __restrict__ h1, int* __restrict__ bs1,
                                                     int P) {
    int arr = blockIdx.y;
    const int* hist = arr ? h1 : h0;
    int* bs = arr ? bs1 : bs0;
    int b = blockIdx.x;
    __shared__ int s[256];
    int t = threadIdx.x;
    s[t] = (t < P) ? hist[b * P + t] : 0;
    __syncthreads();
    for (int off = 128; off; off >>= 1) {
        if (t < off) s[t] += s[t + off];
        __syncthreads();
    }
    if (t == 0) bs[b] = s[0];
}

// bscan: exclusive scan of bucket totals -> bbase; rp[n]=E. grid(2).
__global__ __launch_bounds__(256) void bscan_kernel(const int* __restrict__ bs0, int* __restrict__ bb0, int* __restrict__ rp0, int e0,
                                                    const int* __restrict__ bs1, int* __restrict__ bb1, int* __restrict__ rp1, int e1,
                                                    int nb, int n) {
    int arr = blockIdx.x;
    const int* bsum = arr ? bs1 : bs0;
    int* bb = arr ? bb1 : bb0;
    int* rp = arr ? rp1 : rp0;
    int E = arr ? e1 : e0;
    __shared__ int s[256];
    int t = threadIdx.x;
    int v = (t < nb) ? bsum[t] : 0;
    s[t] = v;
    __syncthreads();
    for (int off = 1; off < 256; off <<= 1) {
        int u = (t >= off) ? s[t - off] : 0;
        __syncthreads();
        s[t] += u;
        __syncthreads();
    }
    if (t < nb) bb[t] = s[t] - v;
    if (t == 0) { bb[nb] = E; rp[n] = E; }
}

// offs: exclusive scan over partitions per bucket, + bbase[b]. In-place. grid (nb, 2).
__global__ __launch_bounds__(256) void offs_kernel(int* __restrict__ h0, const int* __restrict__ bb0,
                                                   int* __restrict__ h1, const int* __restrict__ bb1,
                                                   int P) {
    int arr = blockIdx.y;
    int* hist = arr ? h1 : h0;
    const int* bb = arr ? bb1 : bb0;
    int b = blockIdx.x;
    __shared__ int s[256];
    int t = threadIdx.x;
    int v = (t < P) ? hist[b * P + t] : 0;
    s[t] = v;
    __syncthreads();
    for (int off = 1; off < 256; off <<= 1) {
        int u = (t >= off) ? s[t - off] : 0;
        __syncthreads();
        s[t] += u;
        __syncthreads();
    }
    if (t < P) hist[b * P + t] = s[t] - v + bb[b];
}

// scatter1: chunk p -> bucket-contiguous binned via LDS bump counters, plain stores. grid (P, 2).
__global__ __launch_bounds__(256) void scatter1_kernel(
    const int* __restrict__ src0, const int* __restrict__ dst0, const int* __restrict__ h0, unsigned* __restrict__ binned0,
    const int* __restrict__ src1, const int* __restrict__ dst1, const int* __restrict__ h1, unsigned* __restrict__ binned1,
    int e0, int e1, int nb, int P) {
    int arr = blockIdx.y;
    const int* src = arr ? src1 : src0;
    const int* dst = arr ? dst1 : dst0;
    const int* hist = arr ? h1 : h0;
    unsigned* binned = arr ? binned1 : binned0;
    int e = arr ? e1 : e0;
    int p = blockIdx.x;
    __shared__ int cnt[256];
    int t = threadIdx.x;
    if (t < nb) cnt[t] = hist[t * P + p];
    __syncthreads();
    int base = p * CH;
    int hi = min(base + CH, e);
    for (int i = base + t; i < hi; i += 256) {
        int d = dst[i];
        int pos = atomicAdd(&cnt[d >> SB], 1);        // LDS atomic
        binned[pos] = ((unsigned)d << 16) | (unsigned)src[i];
    }
}

// place: per bucket: LDS node histogram + local scan -> rp[node] and dense u16 CSR. grid (nb, 2).
__global__ __launch_bounds__(256) void place_kernel(
    const unsigned* __restrict__ binned0, const int* __restrict__ bb0, int* __restrict__ rp0, u16* __restrict__ csr0,
    const unsigned* __restrict__ binned1, const int* __restrict__ bb1, int* __restrict__ rp1, u16* __restrict__ csr1,
    int n, int nb) {
    int arr = blockIdx.y;
    const unsigned* binned = arr ? binned1 : binned0;
    const int* bb = arr ? bb1 : bb0;
    int* rp = arr ? rp1 : rp0;
    u16* csr = arr ? csr1 : csr0;
    int b = blockIdx.x;
    __shared__ int cnt[256];
    __shared__ int s[256];
    int t = threadIdx.x;
    int base = bb[b], end = bb[b + 1];
    cnt[t] = 0;
    __syncthreads();
    for (int i = base + t; i < end; i += 256)
        atomicAdd(&cnt[(binned[i] >> 16) & 255], 1);   // LDS atomic
    __syncthreads();
    int deg = cnt[t];
    s[t] = deg;
    __syncthreads();
    for (int off = 1; off < 256; off <<= 1) {
        int u = (t >= off) ? s[t - off] : 0;
        __syncthreads();
        s[t] += u;
        __syncthreads();
    }
    int gpos = base + s[t] - deg;
    int node = (b << SB) + t;
    if (node < n) rp[node] = gpos;
    cnt[t] = gpos;
    __syncthreads();
    for (int i = base + t; i < end; i += 256) {
        unsigned pk = binned[i];
        int ld = (pk >> 16) & 255;
        int pos = atomicAdd(&cnt[ld], 1);              // LDS atomic
        csr[pos] = (u16)(pk & 0xffffu);
    }
}

// ---------------- streaming MFMA GEMM: C = A @ W.T, bf16 out (G1 stage) ----------------
template <bool F32A>
__global__ __launch_bounds__(256) void mfma_gemm(const void* __restrict__ Av,
                                                 const u16* __restrict__ W,
                                                 u16* __restrict__ C, int M, int NC) {
    __shared__ u16 Bs[32 * 512];   // 32 frags x 64 lanes x 8 shorts = 32 KB
    const int t = threadIdx.x;
    const int colBase = blockIdx.y * 128;
#pragma unroll
    for (int i = 0; i < 8; ++i) {               // stage 128x128 W tile, swizzled
        int id = t + 256 * i;
        int nrow = id >> 4, cc = id & 15;
        int f = ((nrow >> 4) << 2) | (cc >> 2);
        int dl = ((cc & 3) << 4) | (nrow & 15);
        *(uint4*)&Bs[(f * 64 + dl) * 8] = ((const uint4*)W)[(size_t)(colBase + nrow) * 16 + cc];
    }
    __syncthreads();
    const int w = t >> 6, lane = t & 63, r = lane & 15, half = lane >> 4;
    const int nTiles = M >> 4;
    const int nWaves = gridDim.x * 4;
    const u16* bB = &Bs[lane * 8];
    for (int tile = blockIdx.x * 4 + w; tile < nTiles; tile += nWaves) {
        int rowA = (tile << 4) + r;
        short8 af[4];
        if (F32A) {
            const float4* Arow = (const float4*)Av + (size_t)rowA * 32 + half * 2;
#pragma unroll
            for (int kk = 0; kk < 4; ++kk) {
                float4 a = Arow[kk * 8], b = Arow[kk * 8 + 1];
                uint4 v = make_uint4(pack2(a.x, a.y), pack2(a.z, a.w),
                                     pack2(b.x, b.y), pack2(b.z, b.w));
                af[kk] = *(short8*)&v;
            }
        } else {
            const uint4* Arow = (const uint4*)Av + (size_t)rowA * 16 + half;
#pragma unroll
            for (int kk = 0; kk < 4; ++kk) {
                uint4 v = Arow[kk * 4];
                af[kk] = *(short8*)&v;
            }
        }
        f32x4 acc[8];
#pragma unroll
        for (int i = 0; i < 8; ++i) acc[i] = (f32x4){0.f, 0.f, 0.f, 0.f};
#pragma unroll
        for (int kk = 0; kk < 4; ++kk)
#pragma unroll
            for (int ct = 0; ct < 8; ++ct) {
                short8 bf = *(const short8*)(bB + (ct * 4 + kk) * 512);
                acc[ct] = __builtin_amdgcn_mfma_f32_16x16x32_bf16(af[kk], bf, acc[ct], 0, 0, 0);
            }
#pragma unroll
        for (int ct = 0; ct < 8; ++ct) {
            int col = colBase + ct * 16 + r;
#pragma unroll
            for (int reg = 0; reg < 4; ++reg) {
                int row = (tile << 4) + half * 4 + reg;
                C[(size_t)row * NC + col] = f2bf(acc[ct][reg]);
            }
        }
    }
}

// ---------------- fused G2: G2 = (mean_nbr0(G1L)+G1M+bl1) @ [Wl2;Wr2].T ----------------
// A-frags built in registers by a CSR gather-mean; W (256x128) staged once (64 KB).
// All 256 output cols per tile so the gather is done exactly once. M % 16 == 0.
__global__ __launch_bounds__(256) void g2_fused_kernel(const u16* __restrict__ G1,
                                                       const u16* __restrict__ csr,
                                                       const int* __restrict__ rp,
                                                       const float* __restrict__ bl1,
                                                       const u16* __restrict__ W,
                                                       u16* __restrict__ G2, int M) {
    __shared__ u16 Bs[64 * 512];   // 64 KB
    __shared__ float bls[128];
    const int t = threadIdx.x;
#pragma unroll
    for (int i = 0; i < 16; ++i) {
        int id = t + 256 * i;
        int nrow = id >> 4, cc = id & 15;
        int f = ((nrow >> 4) << 2) | (cc >> 2);
        int dl = ((cc & 3) << 4) | (nrow & 15);
        *(uint4*)&Bs[(f * 64 + dl) * 8] = ((const uint4*)W)[(size_t)nrow * 16 + cc];
    }
    if (t < 128) bls[t] = bl1[t];
    __syncthreads();
    const int w = t >> 6, lane = t & 63, r = lane & 15, half = lane >> 4;
    const int nTiles = M >> 4;
    const uint4* G14 = (const uint4*)G1;
    const u16* bB = &Bs[lane * 8];
    for (int tile = blockIdx.x * 4 + w; tile < nTiles; tile += gridDim.x * 4) {
        int row = (tile << 4) + r;
        int start = rp[row], end = rp[row + 1];
        float acc[4][8];
#pragma unroll
        for (int kk = 0; kk < 4; ++kk)
#pragma unroll
            for (int j = 0; j < 8; ++j) acc[kk][j] = 0.f;
        int e = start;
        for (; e + 1 < end; e += 2) {
            int s0 = csr[e], s1 = csr[e + 1];
#pragma unroll
            for (int kk = 0; kk < 4; ++kk) {
                uint4 v0 = G14[(size_t)s0 * 48 + kk * 4 + half];
                uint4 v1 = G14[(size_t)s1 * 48 + kk * 4 + half];
                acc[kk][0] += bf_lo(v0.x) + bf_lo(v1.x); acc[kk][1] += bf_hi(v0.x) + bf_hi(v1.x);
                acc[kk][2] += bf_lo(v0.y) + bf_lo(v1.y); acc[kk][3] += bf_hi(v0.y) + bf_hi(v1.y);
                acc[kk][4] += bf_lo(v0.z) + bf_lo(v1.z); acc[kk][5] += bf_hi(v0.z) + bf_hi(v1.z);
                acc[kk][6] += bf_lo(v0.w) + bf_lo(v1.w); acc[kk][7] += bf_hi(v0.w) + bf_hi(v1.w);
            }
        }
        if (e < end) {
            int s0 = csr[e];
#pragma unroll
            for (int kk = 0; kk < 4; ++kk) {
                uint4 v0 = G14[(size_t)s0 * 48 + kk * 4 + half];
                acc[kk][0] += bf_lo(v0.x); acc[kk][1] += bf_hi(v0.x);
                acc[kk][2] += bf_lo(v0.y); acc[kk][3] += bf_hi(v0.y);
                acc[kk][4] += bf_lo(v0.z); acc[kk][5] += bf_hi(v0.z);
                acc[kk][6] += bf_lo(v0.w); acc[kk][7] += bf_hi(v0.w);
            }
        }
        float sc = 1.0f / (float)max(end - start, 1);
        short8 af[4];
#pragma unroll
        for (int kk = 0; kk < 4; ++kk) {
            uint4 m = G14[(size_t)row * 48 + 16 + kk * 4 + half];
            const float* bp = &bls[half * 8 + kk * 32];
            uint4 vv;
            vv.x = pack2(acc[kk][0] * sc + bf_lo(m.x) + bp[0], acc[kk][1] * sc + bf_hi(m.x) + bp[1]);
            vv.y = pack2(acc[kk][2] * sc + bf_lo(m.y) + bp[2], acc[kk][3] * sc + bf_hi(m.y) + bp[3]);
            vv.z = pack2(acc[kk][4] * sc + bf_lo(m.z) + bp[4], acc[kk][5] * sc + bf_hi(m.z) + bp[5]);
            vv.w = pack2(acc[kk][6] * sc + bf_lo(m.w) + bp[6], acc[kk][7] * sc + bf_hi(m.w) + bp[7]);
            af[kk] = *(short8*)&vv;
        }
        f32x4 C[16];
#pragma unroll
        for (int i = 0; i < 16; ++i) C[i] = (f32x4){0.f, 0.f, 0.f, 0.f};
#pragma unroll
        for (int kk = 0; kk < 4; ++kk)
#pragma unroll
            for (int ct = 0; ct < 16; ++ct) {
                short8 bf = *(const short8*)(bB + (ct * 4 + kk) * 512);
                C[ct] = __builtin_amdgcn_mfma_f32_16x16x32_bf16(af[kk], bf, C[ct], 0, 0, 0);
            }
#pragma unroll
        for (int ct = 0; ct < 16; ++ct) {
            int col = ct * 16 + r;
#pragma unroll
            for (int reg = 0; reg < 4; ++reg) {
                int orow = (tile << 4) + half * 4 + reg;
                G2[(size_t)orow * 256 + col] = f2bf(C[ct][reg]);
            }
        }
    }
}

// ---------------- fused head: out = relu((mean_nbr1(G2L)+G2R+G1R+bl2+bs)@W1.T+b1)@W2.T+b2 ----------------
__global__ __launch_bounds__(256) void out_fused_kernel(const u16* __restrict__ G2,
                                                        const u16* __restrict__ G1,
                                                        const u16* __restrict__ csr,
                                                        const int* __restrict__ rp,
                                                        const float* __restrict__ bl2,
                                                        const float* __restrict__ bsk,
                                                        const u16* __restrict__ W1,
                                                        const float* __restrict__ b1,
                                                        const float* __restrict__ W2,
                                                        const float* __restrict__ b2,
                                                        float* __restrict__ out, int M) {
    __shared__ u16 Bs[64 * 512];   // 64 KB
    __shared__ float w2s[768];
    __shared__ float b1s[256];
    __shared__ float bls[128];
    const int t = threadIdx.x;
#pragma unroll
    for (int i = 0; i < 16; ++i) {
        int id = t + 256 * i;
        int nrow = id >> 4, cc = id & 15;
        int f = ((nrow >> 4) << 2) | (cc >> 2);
        int dl = ((cc & 3) << 4) | (nrow & 15);
        *(uint4*)&Bs[(f * 64 + dl) * 8] = ((const uint4*)W1)[(size_t)nrow * 16 + cc];
    }
    for (int i = t; i < 768; i += 256) w2s[i] = W2[i];
    b1s[t] = b1[t];
    if (t < 128) bls[t] = bl2[t] + bsk[t];
    __syncthreads();
    const int w = t >> 6, lane = t & 63, r = lane & 15, half = lane >> 4;
    const int nTiles = M >> 4;
    const uint4* G24 = (const uint4*)G2;
    const uint4* G14 = (const uint4*)G1;
    const u16* bB = &Bs[lane * 8];
    float c0 = b2[0], c1 = b2[1], c2 = b2[2];
    for (int tile = blockIdx.x * 4 + w; tile < nTiles; tile += gridDim.x * 4) {
        int row = (tile << 4) + r;
        int start = rp[row], end = rp[row + 1];
        float acc[4][8];
#pragma unroll
        for (int kk = 0; kk < 4; ++kk)
#pragma unroll
            for (int j = 0; j < 8; ++j) acc[kk][j] = 0.f;
        int e = start;
        for (; e + 1 < end; e += 2) {
            int s0 = csr[e], s1 = csr[e + 1];
#pragma unroll
            for (int kk = 0; kk < 4; ++kk) {
                uint4 v0 = G24[(size_t)s0 * 32 + kk * 4 + half];
                uint4 v1 = G24[(size_t)s1 * 32 + kk * 4 + half];
                acc[kk][0] += bf_lo(v0.x) + bf_lo(v1.x); acc[kk][1] += bf_hi(v0.x) + bf_hi(v1.x);
                acc[kk][2] += bf_lo(v0.y) + bf_lo(v1.y); acc[kk][3] += bf_hi(v0.y) + bf_hi(v1.y);
                acc[kk][4] += bf_lo(v0.z) + bf_lo(v1.z); acc[kk][5] += bf_hi(v0.z) + bf_hi(v1.z);
                acc[kk][6] += bf_lo(v0.w) + bf_lo(v1.w); acc[kk][7] += bf_hi(v0.w) + bf_hi(v1.w);
            }
        }
        if (e < end) {
            int s0 = csr[e];
#pragma unroll
            for (int kk = 0; kk < 4; ++kk) {
                uint4 v0 = G24[(size_t)s0 * 32 + kk * 4 + half];
                acc[kk][0] += bf_lo(v0.x); acc[kk][1] += bf_hi(v0.x);
                acc[kk][2] += bf_lo(v0.y); acc[kk][3] += bf_hi(v0.y);
                acc[kk][4] += bf_lo(v0.z); acc[kk][5] += bf_hi(v0.z);
                acc[kk][6] += bf_lo(v0.w); acc[kk][7] += bf_hi(v0.w);
            }
        }
        float sc = 1.0f / (float)max(end - start, 1);
        short8 af[4];
#pragma unroll
        for (int kk = 0; kk < 4; ++kk) {
            uint4 m2 = G24[(size_t)row * 32 + 16 + kk * 4 + half];
            uint4 m1 = G14[(size_t)row * 48 + 32 + kk * 4 + half];
            const float* bp = &bls[half * 8 + kk * 32];
            uint4 vv;
            vv.x = pack2(acc[kk][0] * sc + bf_lo(m2.x) + bf_lo(m1.x) + bp[0],
                         acc[kk][1] * sc + bf_hi(m2.x) + bf_hi(m1.x) + bp[1]);
            vv.y = pack2(acc[kk][2] * sc + bf_lo(m2.y) + bf_lo(m1.y) + bp[2],
                         acc[kk][3] * sc + bf_hi(m2.y) + bf_hi(m1.y) + bp[3]);
            vv.z = pack2(acc[kk][4] * sc + bf_lo(m2.z) + bf_lo(m1.z) + bp[4],
                         acc[kk][5] * sc + bf_hi(m2.z) + bf_hi(m1.z) + bp[5]);
            vv.w = pack2(acc[kk][6] * sc + bf_lo(m2.w) + bf_lo(m1.w) + bp[6],
                         acc[kk][7] * sc + bf_hi(m2.w) + bf_hi(m1.w) + bp[7]);
            af[kk] = *(short8*)&vv;
        }
        f32x4 C[16];
#pragma unroll
        for (int i = 0; i < 16; ++i) C[i] = (f32x4){0.f, 0.f, 0.f, 0.f};
#pragma unroll
        for (int kk = 0; kk < 4; ++kk)
#pragma unroll
            for (int ct = 0; ct < 16; ++ct) {
                short8 bf = *(const short8*)(bB + (ct * 4 + kk) * 512);
                C[ct] = __builtin_amdgcn_mfma_f32_16x16x32_bf16(af[kk], bf, C[ct], 0, 0, 0);
            }
        float p[4][3] = {{0.f, 0.f, 0.f}, {0.f, 0.f, 0.f}, {0.f, 0.f, 0.f}, {0.f, 0.f, 0.f}};
#pragma unroll
        for (int ct = 0; ct < 16; ++ct) {
            int col = ct * 16 + r;
            float bv = b1s[col];
            float w0 = w2s[col], w1 = w2s[256 + col], w2v = w2s[512 + col];
#pragma unroll
            for (int reg = 0; reg < 4; ++reg) {
                float h4 = fmaxf(C[ct][reg] + bv, 0.f);
                p[reg][0] += h4 * w0;
                p[reg][1] += h4 * w1;
                p[reg][2] += h4 * w2v;
            }
        }
#pragma unroll
        for (int m = 1; m < 16; m <<= 1)
#pragma unroll
            for (int reg = 0; reg < 4; ++reg) {
                p[reg][0] += __shfl_xor(p[reg][0], m);
                p[reg][1] += __shfl_xor(p[reg][1], m);
                p[reg][2] += __shfl_xor(p[reg][2], m);
            }
        if (r == 0) {
#pragma unroll
            for (int reg = 0; reg < 4; ++reg) {
                int orow = (tile << 4) + half * 4 + reg;
                out[(size_t)orow * 3 + 0] = p[reg][0] + c0;
                out[(size_t)orow * 3 + 1] = p[reg][1] + c1;
                out[(size_t)orow * 3 + 2] = p[reg][2] + c2;
            }
        }
    }
}

extern "C" void kernel_launch(void* const* d_in, const int* in_sizes, int n_in,
                              void* d_out, int out_size, void* d_ws, size_t ws_size,
                              hipStream_t stream) {
    const float* x   = (const float*)d_in[0];
    const int*   ei0 = (const int*)d_in[1];
    const int*   ei1 = (const int*)d_in[2];
    const float* Wl1 = (const float*)d_in[3];
    const float* bl1 = (const float*)d_in[4];
    const float* Wr1 = (const float*)d_in[5];
    const float* Wl2 = (const float*)d_in[6];
    const float* bl2 = (const float*)d_in[7];
    const float* Wr2 = (const float*)d_in[8];
    const float* Wsk = (const float*)d_in[9];
    const float* bsk = (const float*)d_in[10];
    const float* W1  = (const float*)d_in[11];
    const float* b1  = (const float*)d_in[12];
    const float* W2  = (const float*)d_in[13];
    const float* b2  = (const float*)d_in[14];
    float* out = (float*)d_out;

    const int N  = in_sizes[0] / DD;   // 50000
    const int E0 = in_sizes[1] / 2;    // 800000
    const int E1 = in_sizes[2] / 2;
    const int H  = in_sizes[12];       // 256

    const int* src0 = ei0;      const int* dst0 = ei0 + E0;
    const int* src1 = ei1;      const int* dst1 = ei1 + E1;

    const int nb   = (N + 255) >> SB;                  // 196 buckets
    const int Emax = (E0 > E1) ? E0 : E1;
    const int P    = (Emax + CH - 1) / CH;             // 98 partitions (<= 256)

    // workspace carve (256B aligned)
    char* wp = (char*)d_ws;
    auto carve = [&](size_t bytes) { char* p = wp; wp += (bytes + 255) & ~(size_t)255; return p; };
    u16* G1   = (u16*)carve((size_t)N * 384 * 2);
    u16* G2   = (u16*)carve((size_t)N * 256 * 2);
    u16* wc1  = (u16*)carve((size_t)384 * DD * 2);   // [Wl1;Wr1;Ws]
    u16* wc2  = (u16*)carve((size_t)256 * DD * 2);   // [Wl2;Wr2]
    u16* w1h  = (u16*)carve((size_t)H * DD * 2);
    int* rp0  = (int*)carve((size_t)(N + 1) * 4);
    int* rp1  = (int*)carve((size_t)(N + 1) * 4);
    u16* csr0 = (u16*)carve((size_t)E0 * 2);
    u16* csr1 = (u16*)carve((size_t)E1 * 2);
    unsigned* binned0 = (unsigned*)carve((size_t)E0 * 4);
    unsigned* binned1 = (unsigned*)carve((size_t)E1 * 4);
    int* hist1_0 = (int*)carve((size_t)nb * P * 4);
    int* hist1_1 = (int*)carve((size_t)nb * P * 4);
    int* bsum0 = (int*)carve((size_t)nb * 4);
    int* bsum1 = (int*)carve((size_t)nb * 4);
    int* bb0 = (int*)carve((size_t)(nb + 1) * 4);
    int* bb1 = (int*)carve((size_t)(nb + 1) * 4);

    // weight cast into concat slots
    CastJobs jb;
    const float* srcs[6] = {Wl1, Wr1, Wsk, Wl2, Wr2, W1};
    u16* dsts[6] = {wc1, wc1 + 128 * DD, wc1 + 256 * DD, wc2, wc2 + 128 * DD, w1h};
    int  cnts[6] = {DD * DD, DD * DD, DD * DD, DD * DD, DD * DD, H * DD};
    int q = 0;
    for (int i = 0; i < 6; ++i) {
        jb.src[i] = (const float4*)srcs[i];
        jb.dst[i] = (uint2*)dsts[i];
        jb.qstart[i] = q;
        q += cnts[i] / 4;
    }
    jb.qstart[6] = q;

    cast_kernel<<<(q + 255) / 256, 256, 0, stream>>>(jb);
    hist1_kernel<<<dim3(P, 2), 256, 0, stream>>>(dst0, hist1_0, dst1, hist1_1, E0, E1, nb, P);
    rowsum_kernel<<<dim3(nb, 2), 256, 0, stream>>>(hist1_0, bsum0, hist1_1, bsum1, P);
    bscan_kernel<<<2, 256, 0, stream>>>(bsum0, bb0, rp0, E0, bsum1, bb1, rp1, E1, nb, N);
    offs_kernel<<<dim3(nb, 2), 256, 0, stream>>>(hist1_0, bb0, hist1_1, bb1, P);
    scatter1_kernel<<<dim3(P, 2), 256, 0, stream>>>(src0, dst0, hist1_0, binned0,
                                                    src1, dst1, hist1_1, binned1, E0, E1, nb, P);
    place_kernel<<<dim3(nb, 2), 256, 0, stream>>>(binned0, bb0, rp0, csr0,
                                                  binned1, bb1, rp1, csr1, N, nb);

    // G1 = x @ [Wl1;Wr1;Ws].T  (fp32 A direct-to-register, NC=384)
    mfma_gemm<true><<<dim3(320, 3), 256, 0, stream>>>(x, wc1, G1, N, 384);
    // G2 = (mean_nbr0(G1L) + G1M + bl1) @ [Wl2;Wr2].T   (agg fused into A-load)
    g2_fused_kernel<<<512, 256, 0, stream>>>(G1, csr0, rp0, bl1, wc2, G2, N);
    // out = relu((mean_nbr1(G2L)+G2R+G1R+bl2+bs)@W1.T+b1) @ W2.T + b2
    out_fused_kernel<<<512, 256, 0, stream>>>(G2, G1, csr1, rp1, bl2, bsk,
                                              w1h, b1, W2, b2, out, N);
}

// Round 9
// 272.188 us; speedup vs baseline: 1.3997x; 1.3997x over previous
//
#include <hip/hip_runtime.h>
#include <hip/hip_bf16.h>

// GraphSAGE net on MI355X — linearity-restructured, separate high-occupancy
// gather kernels (r8 lesson: fusing gather into MFMA kernels kills occupancy,
// 8% -> 112us; keep them apart), dense split planes for gathered data:
//   G1 planes [3][N][128] = x @ [Wl1;Wr1;Ws].T   (fp32 A direct-to-register)
//   h1 = mean_nbr0(G1L) + G1M + bl1              (G1L dense 12.8MB -> L2-friendly)
//   G2 planes [2][N][128] = h1 @ [Wl2;Wr2].T
//   h3 = mean_nbr1(G2L) + G2R + G1R + bl2 + bs
//   out = relu(h3@W1.T+b1) @ W2.T + b2           (h4 in registers)
// Streaming GEMM (r6): W staged once frag-swizzled in LDS, zero barriers in
// the tile loop. CSR build = zero-global-atomic partitioned counting sort
// (r3: same-address device atomics ~85ns; r4: spread ones ~32B fabric RMW each).

#define DD 128
#define SB 8               // 256 nodes per bucket
#define CH 8192            // edges per partition chunk
typedef unsigned short u16;
typedef __attribute__((ext_vector_type(8))) short short8;
typedef __attribute__((ext_vector_type(4))) float f32x4;

__device__ inline u16 f2bf(float f) {
    __hip_bfloat16 h = __float2bfloat16(f);
    u16 u;
    __builtin_memcpy(&u, &h, 2);
    return u;
}
__device__ inline unsigned pack2(float lo, float hi) {
    return (unsigned)f2bf(lo) | ((unsigned)f2bf(hi) << 16);
}
__device__ inline float bf_lo(unsigned u) { union { unsigned x; float f; } c; c.x = u << 16; return c.f; }
__device__ inline float bf_hi(unsigned u) { union { unsigned x; float f; } c; c.x = u & 0xffff0000u; return c.f; }

// ---------------- weight cast fp32 -> bf16 (concat slots) ----------------
struct CastJobs {
    const float4* src[6];
    uint2* dst[6];
    int qstart[7];
};
__global__ __launch_bounds__(256) void cast_kernel(CastJobs jb) {
    int q = blockIdx.x * 256 + threadIdx.x;
    if (q >= jb.qstart[6]) return;
    int i = 0;
#pragma unroll
    for (int k = 1; k < 6; ++k) if (q >= jb.qstart[k]) i = k;
    int local = q - jb.qstart[i];
    float4 v = jb.src[i][local];
    jb.dst[i][local] = make_uint2(pack2(v.x, v.y), pack2(v.z, v.w));
}

// ---------------- CSR build ----------------
// hist1: per-(bucket,partition) counts via LDS histogram. grid (P, 2).
__global__ __launch_bounds__(256) void hist1_kernel(const int* __restrict__ dst0, int* __restrict__ h0,
                                                    const int* __restrict__ dst1, int* __restrict__ h1,
                                                    int e0, int e1, int nb, int P) {
    int arr = blockIdx.y;
    const int* dst = arr ? dst1 : dst0;
    int* hist = arr ? h1 : h0;
    int e = arr ? e1 : e0;
    __shared__ int h[256];
    int t = threadIdx.x;
    h[t] = 0;
    __syncthreads();
    int base = blockIdx.x * CH;
    int hi = min(base + CH, e);
    for (int i = base + t; i < hi; i += 256) atomicAdd(&h[dst[i] >> SB], 1);
    __syncthreads();
    if (t < nb) hist[t * P + blockIdx.x] = h[t];   // [bucket][partition]
}

// bscan: bucket totals (row-sum over partitions) -> exclusive scan -> bbase; rp[n]=E. grid(2).
__global__ __launch_bounds__(256) void bscan_kernel(const int* __restrict__ h0, int* __restrict__ bb0, int* __restrict__ rp0, int e0,
                                                    const int* __restrict__ h1, int* __restrict__ bb1, int* __restrict__ rp1, int e1,
                                                    int nb, int P, int n) {
    int arr = blockIdx.x;
    const int* hist = arr ? h1 : h0;
    int* bb = arr ? bb1 : bb0;
    int* rp = arr ? rp1 : rp0;
    int E = arr ? e1 : e0;
    __shared__ int s[256];
    int t = threadIdx.x;
    int v = 0;
    if (t < nb) {
        const int* row = hist + (size_t)t * P;
        for (int p = 0; p < P; ++p) v += row[p];
    }
    s[t] = v;
    __syncthreads();
    for (int off = 1; off < 256; off <<= 1) {
        int u = (t >= off) ? s[t - off] : 0;
        __syncthreads();
        s[t] += u;
        __syncthreads();
    }
    if (t < nb) bb[t] = s[t] - v;
    if (t == 0) { bb[nb] = E; rp[n] = E; }
}

// offs: exclusive scan over partitions per bucket, + bbase[b]. In-place. grid (nb, 2).
__global__ __launch_bounds__(256) void offs_kernel(int* __restrict__ h0, const int* __restrict__ bb0,
                                                   int* __restrict__ h1, const int* __restrict__ bb1,
                                                   int P) {
    int arr = blockIdx.y;
    int* hist = arr ? h1 : h0;
    const int* bb = arr ? bb1 : bb0;
    int b = blockIdx.x;
    __shared__ int s[256];
    int t = threadIdx.x;
    int v = (t < P) ? hist[b * P + t] : 0;
    s[t] = v;
    __syncthreads();
    for (int off = 1; off < 256; off <<= 1) {
        int u = (t >= off) ? s[t - off] : 0;
        __syncthreads();
        s[t] += u;
        __syncthreads();
    }
    if (t < P) hist[b * P + t] = s[t] - v + bb[b];
}

// scatter1: chunk p -> bucket-contiguous binned via LDS bump counters, plain stores. grid (P, 2).
__global__ __launch_bounds__(256) void scatter1_kernel(
    const int* __restrict__ src0, const int* __restrict__ dst0, const int* __restrict__ h0, unsigned* __restrict__ binned0,
    const int* __restrict__ src1, const int* __restrict__ dst1, const int* __restrict__ h1, unsigned* __restrict__ binned1,
    int e0, int e1, int nb, int P) {
    int arr = blockIdx.y;
    const int* src = arr ? src1 : src0;
    const int* dst = arr ? dst1 : dst0;
    const int* hist = arr ? h1 : h0;
    unsigned* binned = arr ? binned1 : binned0;
    int e = arr ? e1 : e0;
    int p = blockIdx.x;
    __shared__ int cnt[256];
    int t = threadIdx.x;
    if (t < nb) cnt[t] = hist[t * P + p];
    __syncthreads();
    int base = p * CH;
    int hi = min(base + CH, e);
    for (int i = base + t; i < hi; i += 256) {
        int d = dst[i];
        int pos = atomicAdd(&cnt[d >> SB], 1);        // LDS atomic
        binned[pos] = ((unsigned)d << 16) | (unsigned)src[i];
    }
}

// place: per bucket: LDS node histogram + local scan -> rp[node] and dense u16 CSR. grid (nb, 2).
__global__ __launch_bounds__(256) void place_kernel(
    const unsigned* __restrict__ binned0, const int* __restrict__ bb0, int* __restrict__ rp0, u16* __restrict__ csr0,
    const unsigned* __restrict__ binned1, const int* __restrict__ bb1, int* __restrict__ rp1, u16* __restrict__ csr1,
    int n, int nb) {
    int arr = blockIdx.y;
    const unsigned* binned = arr ? binned1 : binned0;
    const int* bb = arr ? bb1 : bb0;
    int* rp = arr ? rp1 : rp0;
    u16* csr = arr ? csr1 : csr0;
    int b = blockIdx.x;
    __shared__ int cnt[256];
    __shared__ int s[256];
    int t = threadIdx.x;
    int base = bb[b], end = bb[b + 1];
    cnt[t] = 0;
    __syncthreads();
    for (int i = base + t; i < end; i += 256)
        atomicAdd(&cnt[(binned[i] >> 16) & 255], 1);   // LDS atomic
    __syncthreads();
    int deg = cnt[t];
    s[t] = deg;
    __syncthreads();
    for (int off = 1; off < 256; off <<= 1) {
        int u = (t >= off) ? s[t - off] : 0;
        __syncthreads();
        s[t] += u;
        __syncthreads();
    }
    int gpos = base + s[t] - deg;
    int node = (b << SB) + t;
    if (node < n) rp[node] = gpos;
    cnt[t] = gpos;
    __syncthreads();
    for (int i = base + t; i < end; i += 256) {
        unsigned pk = binned[i];
        int ld = (pk >> 16) & 255;
        int pos = atomicAdd(&cnt[ld], 1);              // LDS atomic
        csr[pos] = (u16)(pk & 0xffffu);
    }
}

// ---------------- agg layer 1: h1 = mean_nbr(G1L) + G1M + bl1 ----------------
// 16 lanes per node; G1L/G1M are DENSE [N][128] bf16 planes (16 uint4 per row).
__global__ __launch_bounds__(256) void agg1_kernel(const uint4* __restrict__ G1L,
                                                   const uint4* __restrict__ G1M,
                                                   const u16* __restrict__ csr,
                                                   const int* __restrict__ rp,
                                                   const float* __restrict__ bl1,
                                                   u16* __restrict__ h1, int n) {
    int g = (blockIdx.x * 256 + threadIdx.x) >> 4;
    int lane = threadIdx.x & 15;
    if (g >= n) return;
    int start = rp[g], end = rp[g + 1];
    int d = end - start;
    float acc[8] = {0.f, 0.f, 0.f, 0.f, 0.f, 0.f, 0.f, 0.f};
    int e = start;
    for (; e + 3 < end; e += 4) {
        int s0 = csr[e], s1 = csr[e + 1], s2 = csr[e + 2], s3 = csr[e + 3];
        uint4 v0 = G1L[(size_t)s0 * 16 + lane];
        uint4 v1 = G1L[(size_t)s1 * 16 + lane];
        uint4 v2 = G1L[(size_t)s2 * 16 + lane];
        uint4 v3 = G1L[(size_t)s3 * 16 + lane];
        acc[0] += (bf_lo(v0.x) + bf_lo(v1.x)) + (bf_lo(v2.x) + bf_lo(v3.x));
        acc[1] += (bf_hi(v0.x) + bf_hi(v1.x)) + (bf_hi(v2.x) + bf_hi(v3.x));
        acc[2] += (bf_lo(v0.y) + bf_lo(v1.y)) + (bf_lo(v2.y) + bf_lo(v3.y));
        acc[3] += (bf_hi(v0.y) + bf_hi(v1.y)) + (bf_hi(v2.y) + bf_hi(v3.y));
        acc[4] += (bf_lo(v0.z) + bf_lo(v1.z)) + (bf_lo(v2.z) + bf_lo(v3.z));
        acc[5] += (bf_hi(v0.z) + bf_hi(v1.z)) + (bf_hi(v2.z) + bf_hi(v3.z));
        acc[6] += (bf_lo(v0.w) + bf_lo(v1.w)) + (bf_lo(v2.w) + bf_lo(v3.w));
        acc[7] += (bf_hi(v0.w) + bf_hi(v1.w)) + (bf_hi(v2.w) + bf_hi(v3.w));
    }
    for (; e < end; ++e) {
        uint4 v0 = G1L[(size_t)csr[e] * 16 + lane];
        acc[0] += bf_lo(v0.x); acc[1] += bf_hi(v0.x);
        acc[2] += bf_lo(v0.y); acc[3] += bf_hi(v0.y);
        acc[4] += bf_lo(v0.z); acc[5] += bf_hi(v0.z);
        acc[6] += bf_lo(v0.w); acc[7] += bf_hi(v0.w);
    }
    float sc = 1.0f / (float)max(d, 1);
    uint4 m = G1M[(size_t)g * 16 + lane];
    const float4* bl = (const float4*)bl1;
    float4 ba = bl[lane * 2], bb = bl[lane * 2 + 1];
    uint4 r;
    r.x = pack2(acc[0] * sc + bf_lo(m.x) + ba.x, acc[1] * sc + bf_hi(m.x) + ba.y);
    r.y = pack2(acc[2] * sc + bf_lo(m.y) + ba.z, acc[3] * sc + bf_hi(m.y) + ba.w);
    r.z = pack2(acc[4] * sc + bf_lo(m.z) + bb.x, acc[5] * sc + bf_hi(m.z) + bb.y);
    r.w = pack2(acc[6] * sc + bf_lo(m.w) + bb.z, acc[7] * sc + bf_hi(m.w) + bb.w);
    ((uint4*)h1)[(size_t)g * 16 + lane] = r;
}

// ---------------- agg layer 2: h3 = mean_nbr(G2L) + G2R + G1R + bl2 + bs ----------------
// All planes dense [N][128].
__global__ __launch_bounds__(256) void agg2_kernel(const uint4* __restrict__ G2L,
                                                   const uint4* __restrict__ G2R,
                                                   const uint4* __restrict__ G1R,
                                                   const u16* __restrict__ csr,
                                                   const int* __restrict__ rp,
                                                   const float* __restrict__ bl2,
                                                   const float* __restrict__ bs,
                                                   u16* __restrict__ h3, int n) {
    int g = (blockIdx.x * 256 + threadIdx.x) >> 4;
    int lane = threadIdx.x & 15;
    if (g >= n) return;
    int start = rp[g], end = rp[g + 1];
    int d = end - start;
    float acc[8] = {0.f, 0.f, 0.f, 0.f, 0.f, 0.f, 0.f, 0.f};
    int e = start;
    for (; e + 3 < end; e += 4) {
        int s0 = csr[e], s1 = csr[e + 1], s2 = csr[e + 2], s3 = csr[e + 3];
        uint4 v0 = G2L[(size_t)s0 * 16 + lane];
        uint4 v1 = G2L[(size_t)s1 * 16 + lane];
        uint4 v2 = G2L[(size_t)s2 * 16 + lane];
        uint4 v3 = G2L[(size_t)s3 * 16 + lane];
        acc[0] += (bf_lo(v0.x) + bf_lo(v1.x)) + (bf_lo(v2.x) + bf_lo(v3.x));
        acc[1] += (bf_hi(v0.x) + bf_hi(v1.x)) + (bf_hi(v2.x) + bf_hi(v3.x));
        acc[2] += (bf_lo(v0.y) + bf_lo(v1.y)) + (bf_lo(v2.y) + bf_lo(v3.y));
        acc[3] += (bf_hi(v0.y) + bf_hi(v1.y)) + (bf_hi(v2.y) + bf_hi(v3.y));
        acc[4] += (bf_lo(v0.z) + bf_lo(v1.z)) + (bf_lo(v2.z) + bf_lo(v3.z));
        acc[5] += (bf_hi(v0.z) + bf_hi(v1.z)) + (bf_hi(v2.z) + bf_hi(v3.z));
        acc[6] += (bf_lo(v0.w) + bf_lo(v1.w)) + (bf_lo(v2.w) + bf_lo(v3.w));
        acc[7] += (bf_hi(v0.w) + bf_hi(v1.w)) + (bf_hi(v2.w) + bf_hi(v3.w));
    }
    for (; e < end; ++e) {
        uint4 v0 = G2L[(size_t)csr[e] * 16 + lane];
        acc[0] += bf_lo(v0.x); acc[1] += bf_hi(v0.x);
        acc[2] += bf_lo(v0.y); acc[3] += bf_hi(v0.y);
        acc[4] += bf_lo(v0.z); acc[5] += bf_hi(v0.z);
        acc[6] += bf_lo(v0.w); acc[7] += bf_hi(v0.w);
    }
    float sc = 1.0f / (float)max(d, 1);
    uint4 m2 = G2R[(size_t)g * 16 + lane];
    uint4 m1 = G1R[(size_t)g * 16 + lane];
    const float4* c2 = (const float4*)bl2;
    const float4* cs = (const float4*)bs;
    float4 ba = c2[lane * 2], bb = c2[lane * 2 + 1];
    float4 sa = cs[lane * 2], sb = cs[lane * 2 + 1];
    uint4 r;
    r.x = pack2(acc[0] * sc + bf_lo(m2.x) + bf_lo(m1.x) + ba.x + sa.x,
                acc[1] * sc + bf_hi(m2.x) + bf_hi(m1.x) + ba.y + sa.y);
    r.y = pack2(acc[2] * sc + bf_lo(m2.y) + bf_lo(m1.y) + ba.z + sa.z,
                acc[3] * sc + bf_hi(m2.y) + bf_hi(m1.y) + ba.w + sa.w);
    r.z = pack2(acc[4] * sc + bf_lo(m2.z) + bf_lo(m1.z) + bb.x + sb.x,
                acc[5] * sc + bf_hi(m2.z) + bf_hi(m1.z) + bb.y + sb.y);
    r.w = pack2(acc[6] * sc + bf_lo(m2.w) + bf_lo(m1.w) + bb.z + sb.z,
                acc[7] * sc + bf_hi(m2.w) + bf_hi(m1.w) + bb.w + sb.w);
    ((uint4*)h3)[(size_t)g * 16 + lane] = r;
}

// ---------------- streaming MFMA GEMM: C-plane[y] = A @ W[y-block].T, bf16 out ----------------
// Output written to DENSE planes: plane y = C + y*M*128, row-major [M][128].
// W staged once frag-swizzled (32 KB); A-frags global->register; no barriers in loop.
template <bool F32A>
__global__ __launch_bounds__(256) void mfma_gemm(const void* __restrict__ Av,
                                                 const u16* __restrict__ W,
                                                 u16* __restrict__ C, int M) {
    __shared__ u16 Bs[32 * 512];   // 32 KB
    const int t = threadIdx.x;
    const int colBase = blockIdx.y * 128;
    u16* Cp = C + (size_t)blockIdx.y * M * 128;
#pragma unroll
    for (int i = 0; i < 8; ++i) {               // stage 128x128 W tile, swizzled
        int id = t + 256 * i;
        int nrow = id >> 4, cc = id & 15;
        int f = ((nrow >> 4) << 2) | (cc >> 2);
        int dl = ((cc & 3) << 4) | (nrow & 15);
        *(uint4*)&Bs[(f * 64 + dl) * 8] = ((const uint4*)W)[(size_t)(colBase + nrow) * 16 + cc];
    }
    __syncthreads();
    const int w = t >> 6, lane = t & 63, r = lane & 15, half = lane >> 4;
    const int nTiles = M >> 4;
    const int nWaves = gridDim.x * 4;
    const u16* bB = &Bs[lane * 8];
    for (int tile = blockIdx.x * 4 + w; tile < nTiles; tile += nWaves) {
        int rowA = (tile << 4) + r;
        short8 af[4];
        if (F32A) {
            const float4* Arow = (const float4*)Av + (size_t)rowA * 32 + half * 2;
#pragma unroll
            for (int kk = 0; kk < 4; ++kk) {
                float4 a = Arow[kk * 8], b = Arow[kk * 8 + 1];
                uint4 v = make_uint4(pack2(a.x, a.y), pack2(a.z, a.w),
                                     pack2(b.x, b.y), pack2(b.z, b.w));
                af[kk] = *(short8*)&v;
            }
        } else {
            const uint4* Arow = (const uint4*)Av + (size_t)rowA * 16 + half;
#pragma unroll
            for (int kk = 0; kk < 4; ++kk) {
                uint4 v = Arow[kk * 4];
                af[kk] = *(short8*)&v;
            }
        }
        f32x4 acc[8];
#pragma unroll
        for (int i = 0; i < 8; ++i) acc[i] = (f32x4){0.f, 0.f, 0.f, 0.f};
#pragma unroll
        for (int kk = 0; kk < 4; ++kk)
#pragma unroll
            for (int ct = 0; ct < 8; ++ct) {
                short8 bf = *(const short8*)(bB + (ct * 4 + kk) * 512);
                acc[ct] = __builtin_amdgcn_mfma_f32_16x16x32_bf16(af[kk], bf, acc[ct], 0, 0, 0);
            }
#pragma unroll
        for (int ct = 0; ct < 8; ++ct) {
            int col = ct * 16 + r;
#pragma unroll
            for (int reg = 0; reg < 4; ++reg) {
                int row = (tile << 4) + half * 4 + reg;
                Cp[(size_t)row * 128 + col] = f2bf(acc[ct][reg]);
            }
        }
    }
}

// ---------------- fused MLP head: out = relu(h3@W1.T + b1) @ W2.T + b2 ----------------
__global__ __launch_bounds__(256) void gemm_out_kernel(const u16* __restrict__ h3,
                                                       const u16* __restrict__ W1,
                                                       const float* __restrict__ b1,
                                                       const float* __restrict__ W2,
                                                       const float* __restrict__ b2,
                                                       float* __restrict__ out, int M) {
    __shared__ u16 Bs[64 * 512];   // 64 KB
    __shared__ float w2s[3 * 256];
    __shared__ float b1s[256];
    const int t = threadIdx.x;
#pragma unroll
    for (int i = 0; i < 16; ++i) {
        int id = t + 256 * i;
        int nrow = id >> 4, cc = id & 15;
        int f = ((nrow >> 4) << 2) | (cc >> 2);
        int dl = ((cc & 3) << 4) | (nrow & 15);
        *(uint4*)&Bs[(f * 64 + dl) * 8] = ((const uint4*)W1)[(size_t)nrow * 16 + cc];
    }
    for (int i = t; i < 768; i += 256) w2s[i] = W2[i];
    b1s[t] = b1[t];
    __syncthreads();
    const int w = t >> 6, lane = t & 63, r = lane & 15, half = lane >> 4;
    const int nTiles = M >> 4;
    const int nWaves = gridDim.x * 4;
    const u16* bB = &Bs[lane * 8];
    float c0 = b2[0], c1 = b2[1], c2 = b2[2];
    for (int tile = blockIdx.x * 4 + w; tile < nTiles; tile += nWaves) {
        int rowA = (tile << 4) + r;
        const uint4* Arow = (const uint4*)h3 + (size_t)rowA * 16 + half;
        short8 af[4];
#pragma unroll
        for (int kk = 0; kk < 4; ++kk) {
            uint4 v = Arow[kk * 4];
            af[kk] = *(short8*)&v;
        }
        f32x4 acc[16];
#pragma unroll
        for (int i = 0; i < 16; ++i) acc[i] = (f32x4){0.f, 0.f, 0.f, 0.f};
#pragma unroll
        for (int kk = 0; kk < 4; ++kk)
#pragma unroll
            for (int ct = 0; ct < 16; ++ct) {
                short8 bf = *(const short8*)(bB + (ct * 4 + kk) * 512);
                acc[ct] = __builtin_amdgcn_mfma_f32_16x16x32_bf16(af[kk], bf, acc[ct], 0, 0, 0);
            }
        float p[4][3] = {{0.f, 0.f, 0.f}, {0.f, 0.f, 0.f}, {0.f, 0.f, 0.f}, {0.f, 0.f, 0.f}};
#pragma unroll
        for (int ct = 0; ct < 16; ++ct) {
            int col = ct * 16 + r;
            float bv = b1s[col];
            float w0 = w2s[col], w1 = w2s[256 + col], w2v = w2s[512 + col];
#pragma unroll
            for (int reg = 0; reg < 4; ++reg) {
                float h4 = fmaxf(acc[ct][reg] + bv, 0.f);
                p[reg][0] += h4 * w0;
                p[reg][1] += h4 * w1;
                p[reg][2] += h4 * w2v;
            }
        }
#pragma unroll
        for (int m = 1; m < 16; m <<= 1)
#pragma unroll
            for (int reg = 0; reg < 4; ++reg) {
                p[reg][0] += __shfl_xor(p[reg][0], m);
                p[reg][1] += __shfl_xor(p[reg][1], m);
                p[reg][2] += __shfl_xor(p[reg][2], m);
            }
        if (r == 0) {
#pragma unroll
            for (int reg = 0; reg < 4; ++reg) {
                int row = (tile << 4) + half * 4 + reg;
                out[(size_t)row * 3 + 0] = p[reg][0] + c0;
                out[(size_t)row * 3 + 1] = p[reg][1] + c1;
                out[(size_t)row * 3 + 2] = p[reg][2] + c2;
            }
        }
    }
}

extern "C" void kernel_launch(void* const* d_in, const int* in_sizes, int n_in,
                              void* d_out, int out_size, void* d_ws, size_t ws_size,
                              hipStream_t stream) {
    const float* x   = (const float*)d_in[0];
    const int*   ei0 = (const int*)d_in[1];
    const int*   ei1 = (const int*)d_in[2];
    const float* Wl1 = (const float*)d_in[3];
    const float* bl1 = (const float*)d_in[4];
    const float* Wr1 = (const float*)d_in[5];
    const float* Wl2 = (const float*)d_in[6];
    const float* bl2 = (const float*)d_in[7];
    const float* Wr2 = (const float*)d_in[8];
    const float* Wsk = (const float*)d_in[9];
    const float* bsk = (const float*)d_in[10];
    const float* W1  = (const float*)d_in[11];
    const float* b1  = (const float*)d_in[12];
    const float* W2  = (const float*)d_in[13];
    const float* b2  = (const float*)d_in[14];
    float* out = (float*)d_out;

    const int N  = in_sizes[0] / DD;   // 50000
    const int E0 = in_sizes[1] / 2;    // 800000
    const int E1 = in_sizes[2] / 2;
    const int H  = in_sizes[12];       // 256

    const int* src0 = ei0;      const int* dst0 = ei0 + E0;
    const int* src1 = ei1;      const int* dst1 = ei1 + E1;

    const int nb   = (N + 255) >> SB;                  // 196 buckets
    const int Emax = (E0 > E1) ? E0 : E1;
    const int P    = (Emax + CH - 1) / CH;             // 98 partitions

    // workspace carve (256B aligned)
    char* wp = (char*)d_ws;
    auto carve = [&](size_t bytes) { char* p = wp; wp += (bytes + 255) & ~(size_t)255; return p; };
    u16* G1   = (u16*)carve((size_t)3 * N * DD * 2);   // planes: G1L | G1M | G1R
    u16* G2   = (u16*)carve((size_t)2 * N * DD * 2);   // planes: G2L | G2R
    u16* h1h  = (u16*)carve((size_t)N * DD * 2);
    u16* h3h  = (u16*)carve((size_t)N * DD * 2);
    u16* wc1  = (u16*)carve((size_t)384 * DD * 2);     // [Wl1;Wr1;Ws]
    u16* wc2  = (u16*)carve((size_t)256 * DD * 2);     // [Wl2;Wr2]
    u16* w1h  = (u16*)carve((size_t)H * DD * 2);
    int* rp0  = (int*)carve((size_t)(N + 1) * 4);
    int* rp1  = (int*)carve((size_t)(N + 1) * 4);
    u16* csr0 = (u16*)carve((size_t)E0 * 2);
    u16* csr1 = (u16*)carve((size_t)E1 * 2);
    unsigned* binned0 = (unsigned*)carve((size_t)E0 * 4);
    unsigned* binned1 = (unsigned*)carve((size_t)E1 * 4);
    int* hist1_0 = (int*)carve((size_t)nb * P * 4);
    int* hist1_1 = (int*)carve((size_t)nb * P * 4);
    int* bb0 = (int*)carve((size_t)(nb + 1) * 4);
    int* bb1 = (int*)carve((size_t)(nb + 1) * 4);

    const u16* G1L = G1;
    const u16* G1M = G1 + (size_t)N * DD;
    const u16* G1R = G1 + (size_t)2 * N * DD;
    const u16* G2L = G2;
    const u16* G2R = G2 + (size_t)N * DD;

    // weight cast into concat slots
    CastJobs jb;
    const float* srcs[6] = {Wl1, Wr1, Wsk, Wl2, Wr2, W1};
    u16* dsts[6] = {wc1, wc1 + 128 * DD, wc1 + 256 * DD, wc2, wc2 + 128 * DD, w1h};
    int  cnts[6] = {DD * DD, DD * DD, DD * DD, DD * DD, DD * DD, H * DD};
    int q = 0;
    for (int i = 0; i < 6; ++i) {
        jb.src[i] = (const float4*)srcs[i];
        jb.dst[i] = (uint2*)dsts[i];
        jb.qstart[i] = q;
        q += cnts[i] / 4;
    }
    jb.qstart[6] = q;

    const int gAgg = (N * 16 + 255) / 256;

    cast_kernel<<<(q + 255) / 256, 256, 0, stream>>>(jb);
    hist1_kernel<<<dim3(P, 2), 256, 0, stream>>>(dst0, hist1_0, dst1, hist1_1, E0, E1, nb, P);
    bscan_kernel<<<2, 256, 0, stream>>>(hist1_0, bb0, rp0, E0, hist1_1, bb1, rp1, E1, nb, P, N);
    offs_kernel<<<dim3(nb, 2), 256, 0, stream>>>(hist1_0, bb0, hist1_1, bb1, P);
    scatter1_kernel<<<dim3(P, 2), 256, 0, stream>>>(src0, dst0, hist1_0, binned0,
                                                    src1, dst1, hist1_1, binned1, E0, E1, nb, P);
    place_kernel<<<dim3(nb, 2), 256, 0, stream>>>(binned0, bb0, rp0, csr0,
                                                  binned1, bb1, rp1, csr1, N, nb);

    // G1 planes = x @ [Wl1;Wr1;Ws].T  (fp32 A direct-to-register)
    mfma_gemm<true><<<dim3(320, 3), 256, 0, stream>>>(x, wc1, G1, N);
    // h1 = mean_nbr0(G1L) + G1M + bl1   (G1L dense 12.8 MB)
    agg1_kernel<<<gAgg, 256, 0, stream>>>((const uint4*)G1L, (const uint4*)G1M,
                                          csr0, rp0, bl1, h1h, N);
    // G2 planes = h1 @ [Wl2;Wr2].T
    mfma_gemm<false><<<dim3(320, 2), 256, 0, stream>>>(h1h, wc2, G2, N);
    // h3 = mean_nbr1(G2L) + G2R + G1R + bl2 + bs
    agg2_kernel<<<gAgg, 256, 0, stream>>>((const uint4*)G2L, (const uint4*)G2R,
                                          (const uint4*)G1R, csr1, rp1, bl2, bsk, h3h, N);
    // out = relu(h3@W1.T + b1) @ W2.T + b2   (h4 in registers)
    gemm_out_kernel<<<512, 256, 0, stream>>>(h3h, w1h, b1, W2, b2, out, N);
}

// Round 10
// 259.594 us; speedup vs baseline: 1.4676x; 1.0485x over previous
//
#include <hip/hip_runtime.h>
#include <hip/hip_bf16.h>

// GraphSAGE net on MI355X — linearity-restructured, separate high-occupancy
// gather kernels (r8 lesson: fusing gather into MFMA kernels kills occupancy).
//   G1 planes [3][N][128] = x @ [Wl1;Wr1;Ws].T   (fp32 A direct-to-register)
//   h1 = mean_nbr0(G1L) + G1M + bl1
//   G2 planes [2][N][128] = h1 @ [Wl2;Wr2].T
//   h3 = mean_nbr1(G2L) + G2R + G1R + bl2 + bs
//   out = relu(h3@W1.T+b1) @ W2.T + b2           (h4 in registers)
// Agg (r10): ONE WAVE PER NODE, 1 dword (2 bf16)/lane, 8-deep unroll -> 8
// outstanding loads/lane, no inter-node divergence (r9 lesson: gather was
// latency-bound at 4 outstanding; L2 BW needs ~8+ in flight per lane).
// Streaming GEMM (r6): W staged once frag-swizzled in LDS, zero barriers in
// the tile loop. CSR build = zero-global-atomic partitioned counting sort
// (r3: same-address device atomics ~85ns; r4: spread ones ~32B fabric RMW each).

#define DD 128
#define SB 8               // 256 nodes per bucket
#define CH 4096            // edges per partition chunk (r7-proven; 196 partitions)
typedef unsigned short u16;
typedef __attribute__((ext_vector_type(8))) short short8;
typedef __attribute__((ext_vector_type(4))) float f32x4;

__device__ inline u16 f2bf(float f) {
    __hip_bfloat16 h = __float2bfloat16(f);
    u16 u;
    __builtin_memcpy(&u, &h, 2);
    return u;
}
__device__ inline unsigned pack2(float lo, float hi) {
    return (unsigned)f2bf(lo) | ((unsigned)f2bf(hi) << 16);
}
__device__ inline float bf_lo(unsigned u) { union { unsigned x; float f; } c; c.x = u << 16; return c.f; }
__device__ inline float bf_hi(unsigned u) { union { unsigned x; float f; } c; c.x = u & 0xffff0000u; return c.f; }

// ---------------- weight cast fp32 -> bf16 (concat slots) ----------------
struct CastJobs {
    const float4* src[6];
    uint2* dst[6];
    int qstart[7];
};
__global__ __launch_bounds__(256) void cast_kernel(CastJobs jb) {
    int q = blockIdx.x * 256 + threadIdx.x;
    if (q >= jb.qstart[6]) return;
    int i = 0;
#pragma unroll
    for (int k = 1; k < 6; ++k) if (q >= jb.qstart[k]) i = k;
    int local = q - jb.qstart[i];
    float4 v = jb.src[i][local];
    jb.dst[i][local] = make_uint2(pack2(v.x, v.y), pack2(v.z, v.w));
}

// ---------------- CSR build ----------------
// hist1: per-(bucket,partition) counts via LDS histogram. grid (P, 2).
__global__ __launch_bounds__(256) void hist1_kernel(const int* __restrict__ dst0, int* __restrict__ h0,
                                                    const int* __restrict__ dst1, int* __restrict__ h1,
                                                    int e0, int e1, int nb, int P) {
    int arr = blockIdx.y;
    const int* dst = arr ? dst1 : dst0;
    int* hist = arr ? h1 : h0;
    int e = arr ? e1 : e0;
    __shared__ int h[256];
    int t = threadIdx.x;
    h[t] = 0;
    __syncthreads();
    int base = blockIdx.x * CH;
    int hi = min(base + CH, e);
    for (int i = base + t; i < hi; i += 256) atomicAdd(&h[dst[i] >> SB], 1);
    __syncthreads();
    if (t < nb) hist[t * P + blockIdx.x] = h[t];   // [bucket][partition]
}

// rowsum: bucket totals = sum_p hist1[b][p]. grid (nb, 2).
__global__ __launch_bounds__(256) void rowsum_kernel(const int* __restrict__ h0, int* __restrict__ bs0,
                                                     const int* __restrict__ h1, int* __restrict__ bs1,
                                                     int P) {
    int arr = blockIdx.y;
    const int* hist = arr ? h1 : h0;
    int* bs = arr ? bs1 : bs0;
    int b = blockIdx.x;
    __shared__ int s[256];
    int t = threadIdx.x;
    s[t] = (t < P) ? hist[b * P + t] : 0;
    __syncthreads();
    for (int off = 128; off; off >>= 1) {
        if (t < off) s[t] += s[t + off];
        __syncthreads();
    }
    if (t == 0) bs[b] = s[0];
}

// bscan: exclusive scan of bucket totals -> bbase; rp[n]=E. grid(2).
__global__ __launch_bounds__(256) void bscan_kernel(const int* __restrict__ bs0, int* __restrict__ bb0, int* __restrict__ rp0, int e0,
                                                    const int* __restrict__ bs1, int* __restrict__ bb1, int* __restrict__ rp1, int e1,
                                                    int nb, int n) {
    int arr = blockIdx.x;
    const int* bsum = arr ? bs1 : bs0;
    int* bb = arr ? bb1 : bb0;
    int* rp = arr ? rp1 : rp0;
    int E = arr ? e1 : e0;
    __shared__ int s[256];
    int t = threadIdx.x;
    int v = (t < nb) ? bsum[t] : 0;
    s[t] = v;
    __syncthreads();
    for (int off = 1; off < 256; off <<= 1) {
        int u = (t >= off) ? s[t - off] : 0;
        __syncthreads();
        s[t] += u;
        __syncthreads();
    }
    if (t < nb) bb[t] = s[t] - v;
    if (t == 0) { bb[nb] = E; rp[n] = E; }
}

// offs: exclusive scan over partitions per bucket, + bbase[b]. In-place. grid (nb, 2).
__global__ __launch_bounds__(256) void offs_kernel(int* __restrict__ h0, const int* __restrict__ bb0,
                                                   int* __restrict__ h1, const int* __restrict__ bb1,
                                                   int P) {
    int arr = blockIdx.y;
    int* hist = arr ? h1 : h0;
    const int* bb = arr ? bb1 : bb0;
    int b = blockIdx.x;
    __shared__ int s[256];
    int t = threadIdx.x;
    int v = (t < P) ? hist[b * P + t] : 0;
    s[t] = v;
    __syncthreads();
    for (int off = 1; off < 256; off <<= 1) {
        int u = (t >= off) ? s[t - off] : 0;
        __syncthreads();
        s[t] += u;
        __syncthreads();
    }
    if (t < P) hist[b * P + t] = s[t] - v + bb[b];
}

// scatter1: chunk p -> bucket-contiguous binned via LDS bump counters, plain stores. grid (P, 2).
__global__ __launch_bounds__(256) void scatter1_kernel(
    const int* __restrict__ src0, const int* __restrict__ dst0, const int* __restrict__ h0, unsigned* __restrict__ binned0,
    const int* __restrict__ src1, const int* __restrict__ dst1, const int* __restrict__ h1, unsigned* __restrict__ binned1,
    int e0, int e1, int nb, int P) {
    int arr = blockIdx.y;
    const int* src = arr ? src1 : src0;
    const int* dst = arr ? dst1 : dst0;
    const int* hist = arr ? h1 : h0;
    unsigned* binned = arr ? binned1 : binned0;
    int e = arr ? e1 : e0;
    int p = blockIdx.x;
    __shared__ int cnt[256];
    int t = threadIdx.x;
    if (t < nb) cnt[t] = hist[t * P + p];
    __syncthreads();
    int base = p * CH;
    int hi = min(base + CH, e);
    for (int i = base + t; i < hi; i += 256) {
        int d = dst[i];
        int pos = atomicAdd(&cnt[d >> SB], 1);        // LDS atomic
        binned[pos] = ((unsigned)d << 16) | (unsigned)src[i];
    }
}

// place: per bucket: LDS node histogram + local scan -> rp[node] and dense u16 CSR. grid (nb, 2).
__global__ __launch_bounds__(256) void place_kernel(
    const unsigned* __restrict__ binned0, const int* __restrict__ bb0, int* __restrict__ rp0, u16* __restrict__ csr0,
    const unsigned* __restrict__ binned1, const int* __restrict__ bb1, int* __restrict__ rp1, u16* __restrict__ csr1,
    int n, int nb) {
    int arr = blockIdx.y;
    const unsigned* binned = arr ? binned1 : binned0;
    const int* bb = arr ? bb1 : bb0;
    int* rp = arr ? rp1 : rp0;
    u16* csr = arr ? csr1 : csr0;
    int b = blockIdx.x;
    __shared__ int cnt[256];
    __shared__ int s[256];
    int t = threadIdx.x;
    int base = bb[b], end = bb[b + 1];
    cnt[t] = 0;
    __syncthreads();
    for (int i = base + t; i < end; i += 256)
        atomicAdd(&cnt[(binned[i] >> 16) & 255], 1);   // LDS atomic
    __syncthreads();
    int deg = cnt[t];
    s[t] = deg;
    __syncthreads();
    for (int off = 1; off < 256; off <<= 1) {
        int u = (t >= off) ? s[t - off] : 0;
        __syncthreads();
        s[t] += u;
        __syncthreads();
    }
    int gpos = base + s[t] - deg;
    int node = (b << SB) + t;
    if (node < n) rp[node] = gpos;
    cnt[t] = gpos;
    __syncthreads();
    for (int i = base + t; i < end; i += 256) {
        unsigned pk = binned[i];
        int ld = (pk >> 16) & 255;
        int pos = atomicAdd(&cnt[ld], 1);              // LDS atomic
        csr[pos] = (u16)(pk & 0xffffu);
    }
}

// ---------------- agg1: h1 = mean_nbr(G1L) + G1M + bl1 ----------------
// One WAVE per node, one dword (2 bf16 cols) per lane, 8-deep unroll.
__global__ __launch_bounds__(256) void agg1_kernel(const unsigned* __restrict__ G1L,
                                                   const unsigned* __restrict__ G1M,
                                                   const u16* __restrict__ csr,
                                                   const int* __restrict__ rp,
                                                   const float* __restrict__ bl1,
                                                   unsigned* __restrict__ h1, int n) {
    int g = (blockIdx.x * 256 + threadIdx.x) >> 6;
    int lane = threadIdx.x & 63;
    if (g >= n) return;
    int start = rp[g], end = rp[g + 1];
    float a0 = 0.f, a1 = 0.f;
    int e = start;
    for (; e + 7 < end; e += 8) {
        int s0 = csr[e],     s1 = csr[e + 1], s2 = csr[e + 2], s3 = csr[e + 3];
        int s4 = csr[e + 4], s5 = csr[e + 5], s6 = csr[e + 6], s7 = csr[e + 7];
        unsigned v0 = G1L[(size_t)s0 * 64 + lane];
        unsigned v1 = G1L[(size_t)s1 * 64 + lane];
        unsigned v2 = G1L[(size_t)s2 * 64 + lane];
        unsigned v3 = G1L[(size_t)s3 * 64 + lane];
        unsigned v4 = G1L[(size_t)s4 * 64 + lane];
        unsigned v5 = G1L[(size_t)s5 * 64 + lane];
        unsigned v6 = G1L[(size_t)s6 * 64 + lane];
        unsigned v7 = G1L[(size_t)s7 * 64 + lane];
        a0 += ((bf_lo(v0) + bf_lo(v1)) + (bf_lo(v2) + bf_lo(v3))) +
              ((bf_lo(v4) + bf_lo(v5)) + (bf_lo(v6) + bf_lo(v7)));
        a1 += ((bf_hi(v0) + bf_hi(v1)) + (bf_hi(v2) + bf_hi(v3))) +
              ((bf_hi(v4) + bf_hi(v5)) + (bf_hi(v6) + bf_hi(v7)));
    }
    for (; e + 3 < end; e += 4) {
        int s0 = csr[e], s1 = csr[e + 1], s2 = csr[e + 2], s3 = csr[e + 3];
        unsigned v0 = G1L[(size_t)s0 * 64 + lane];
        unsigned v1 = G1L[(size_t)s1 * 64 + lane];
        unsigned v2 = G1L[(size_t)s2 * 64 + lane];
        unsigned v3 = G1L[(size_t)s3 * 64 + lane];
        a0 += (bf_lo(v0) + bf_lo(v1)) + (bf_lo(v2) + bf_lo(v3));
        a1 += (bf_hi(v0) + bf_hi(v1)) + (bf_hi(v2) + bf_hi(v3));
    }
    for (; e < end; ++e) {
        unsigned v0 = G1L[(size_t)csr[e] * 64 + lane];
        a0 += bf_lo(v0);
        a1 += bf_hi(v0);
    }
    float sc = 1.0f / (float)max(end - start, 1);
    unsigned m = G1M[(size_t)g * 64 + lane];
    float2 b = ((const float2*)bl1)[lane];
    h1[(size_t)g * 64 + lane] = pack2(a0 * sc + bf_lo(m) + b.x, a1 * sc + bf_hi(m) + b.y);
}

// ---------------- agg2: h3 = mean_nbr(G2L) + G2R + G1R + bl2 + bs ----------------
__global__ __launch_bounds__(256) void agg2_kernel(const unsigned* __restrict__ G2L,
                                                   const unsigned* __restrict__ G2R,
                                                   const unsigned* __restrict__ G1R,
                                                   const u16* __restrict__ csr,
                                                   const int* __restrict__ rp,
                                                   const float* __restrict__ bl2,
                                                   const float* __restrict__ bs,
                                                   unsigned* __restrict__ h3, int n) {
    int g = (blockIdx.x * 256 + threadIdx.x) >> 6;
    int lane = threadIdx.x & 63;
    if (g >= n) return;
    int start = rp[g], end = rp[g + 1];
    float a0 = 0.f, a1 = 0.f;
    int e = start;
    for (; e + 7 < end; e += 8) {
        int s0 = csr[e],     s1 = csr[e + 1], s2 = csr[e + 2], s3 = csr[e + 3];
        int s4 = csr[e + 4], s5 = csr[e + 5], s6 = csr[e + 6], s7 = csr[e + 7];
        unsigned v0 = G2L[(size_t)s0 * 64 + lane];
        unsigned v1 = G2L[(size_t)s1 * 64 + lane];
        unsigned v2 = G2L[(size_t)s2 * 64 + lane];
        unsigned v3 = G2L[(size_t)s3 * 64 + lane];
        unsigned v4 = G2L[(size_t)s4 * 64 + lane];
        unsigned v5 = G2L[(size_t)s5 * 64 + lane];
        unsigned v6 = G2L[(size_t)s6 * 64 + lane];
        unsigned v7 = G2L[(size_t)s7 * 64 + lane];
        a0 += ((bf_lo(v0) + bf_lo(v1)) + (bf_lo(v2) + bf_lo(v3))) +
              ((bf_lo(v4) + bf_lo(v5)) + (bf_lo(v6) + bf_lo(v7)));
        a1 += ((bf_hi(v0) + bf_hi(v1)) + (bf_hi(v2) + bf_hi(v3))) +
              ((bf_hi(v4) + bf_hi(v5)) + (bf_hi(v6) + bf_hi(v7)));
    }
    for (; e + 3 < end; e += 4) {
        int s0 = csr[e], s1 = csr[e + 1], s2 = csr[e + 2], s3 = csr[e + 3];
        unsigned v0 = G2L[(size_t)s0 * 64 + lane];
        unsigned v1 = G2L[(size_t)s1 * 64 + lane];
        unsigned v2 = G2L[(size_t)s2 * 64 + lane];
        unsigned v3 = G2L[(size_t)s3 * 64 + lane];
        a0 += (bf_lo(v0) + bf_lo(v1)) + (bf_lo(v2) + bf_lo(v3));
        a1 += (bf_hi(v0) + bf_hi(v1)) + (bf_hi(v2) + bf_hi(v3));
    }
    for (; e < end; ++e) {
        unsigned v0 = G2L[(size_t)csr[e] * 64 + lane];
        a0 += bf_lo(v0);
        a1 += bf_hi(v0);
    }
    float sc = 1.0f / (float)max(end - start, 1);
    unsigned m2 = G2R[(size_t)g * 64 + lane];
    unsigned m1 = G1R[(size_t)g * 64 + lane];
    float2 b = ((const float2*)bl2)[lane];
    float2 s2 = ((const float2*)bs)[lane];
    h3[(size_t)g * 64 + lane] = pack2(a0 * sc + bf_lo(m2) + bf_lo(m1) + b.x + s2.x,
                                      a1 * sc + bf_hi(m2) + bf_hi(m1) + b.y + s2.y);
}

// ---------------- streaming MFMA GEMM: C-plane[y] = A @ W[y-block].T, bf16 out ----------------
// Output written to DENSE planes: plane y = C + y*M*128, row-major [M][128].
template <bool F32A>
__global__ __launch_bounds__(256) void mfma_gemm(const void* __restrict__ Av,
                                                 const u16* __restrict__ W,
                                                 u16* __restrict__ C, int M) {
    __shared__ u16 Bs[32 * 512];   // 32 KB
    const int t = threadIdx.x;
    const int colBase = blockIdx.y * 128;
    u16* Cp = C + (size_t)blockIdx.y * M * 128;
#pragma unroll
    for (int i = 0; i < 8; ++i) {               // stage 128x128 W tile, swizzled
        int id = t + 256 * i;
        int nrow = id >> 4, cc = id & 15;
        int f = ((nrow >> 4) << 2) | (cc >> 2);
        int dl = ((cc & 3) << 4) | (nrow & 15);
        *(uint4*)&Bs[(f * 64 + dl) * 8] = ((const uint4*)W)[(size_t)(colBase + nrow) * 16 + cc];
    }
    __syncthreads();
    const int w = t >> 6, lane = t & 63, r = lane & 15, half = lane >> 4;
    const int nTiles = M >> 4;
    const int nWaves = gridDim.x * 4;
    const u16* bB = &Bs[lane * 8];
    for (int tile = blockIdx.x * 4 + w; tile < nTiles; tile += nWaves) {
        int rowA = (tile << 4) + r;
        short8 af[4];
        if (F32A) {
            const float4* Arow = (const float4*)Av + (size_t)rowA * 32 + half * 2;
#pragma unroll
            for (int kk = 0; kk < 4; ++kk) {
                float4 a = Arow[kk * 8], b = Arow[kk * 8 + 1];
                uint4 v = make_uint4(pack2(a.x, a.y), pack2(a.z, a.w),
                                     pack2(b.x, b.y), pack2(b.z, b.w));
                af[kk] = *(short8*)&v;
            }
        } else {
            const uint4* Arow = (const uint4*)Av + (size_t)rowA * 16 + half;
#pragma unroll
            for (int kk = 0; kk < 4; ++kk) {
                uint4 v = Arow[kk * 4];
                af[kk] = *(short8*)&v;
            }
        }
        f32x4 acc[8];
#pragma unroll
        for (int i = 0; i < 8; ++i) acc[i] = (f32x4){0.f, 0.f, 0.f, 0.f};
#pragma unroll
        for (int kk = 0; kk < 4; ++kk)
#pragma unroll
            for (int ct = 0; ct < 8; ++ct) {
                short8 bf = *(const short8*)(bB + (ct * 4 + kk) * 512);
                acc[ct] = __builtin_amdgcn_mfma_f32_16x16x32_bf16(af[kk], bf, acc[ct], 0, 0, 0);
            }
#pragma unroll
        for (int ct = 0; ct < 8; ++ct) {
            int col = ct * 16 + r;
#pragma unroll
            for (int reg = 0; reg < 4; ++reg) {
                int row = (tile << 4) + half * 4 + reg;
                Cp[(size_t)row * 128 + col] = f2bf(acc[ct][reg]);
            }
        }
    }
}

// ---------------- fused MLP head: out = relu(h3@W1.T + b1) @ W2.T + b2 ----------------
__global__ __launch_bounds__(256) void gemm_out_kernel(const u16* __restrict__ h3,
                                                       const u16* __restrict__ W1,
                                                       const float* __restrict__ b1,
                                                       const float* __restrict__ W2,
                                                       const float* __restrict__ b2,
                                                       float* __restrict__ out, int M) {
    __shared__ u16 Bs[64 * 512];   // 64 KB
    __shared__ float w2s[3 * 256];
    __shared__ float b1s[256];
    const int t = threadIdx.x;
#pragma unroll
    for (int i = 0; i < 16; ++i) {
        int id = t + 256 * i;
        int nrow = id >> 4, cc = id & 15;
        int f = ((nrow >> 4) << 2) | (cc >> 2);
        int dl = ((cc & 3) << 4) | (nrow & 15);
        *(uint4*)&Bs[(f * 64 + dl) * 8] = ((const uint4*)W1)[(size_t)nrow * 16 + cc];
    }
    for (int i = t; i < 768; i += 256) w2s[i] = W2[i];
    b1s[t] = b1[t];
    __syncthreads();
    const int w = t >> 6, lane = t & 63, r = lane & 15, half = lane >> 4;
    const int nTiles = M >> 4;
    const int nWaves = gridDim.x * 4;
    const u16* bB = &Bs[lane * 8];
    float c0 = b2[0], c1 = b2[1], c2 = b2[2];
    for (int tile = blockIdx.x * 4 + w; tile < nTiles; tile += nWaves) {
        int rowA = (tile << 4) + r;
        const uint4* Arow = (const uint4*)h3 + (size_t)rowA * 16 + half;
        short8 af[4];
#pragma unroll
        for (int kk = 0; kk < 4; ++kk) {
            uint4 v = Arow[kk * 4];
            af[kk] = *(short8*)&v;
        }
        f32x4 acc[16];
#pragma unroll
        for (int i = 0; i < 16; ++i) acc[i] = (f32x4){0.f, 0.f, 0.f, 0.f};
#pragma unroll
        for (int kk = 0; kk < 4; ++kk)
#pragma unroll
            for (int ct = 0; ct < 16; ++ct) {
                short8 bf = *(const short8*)(bB + (ct * 4 + kk) * 512);
                acc[ct] = __builtin_amdgcn_mfma_f32_16x16x32_bf16(af[kk], bf, acc[ct], 0, 0, 0);
            }
        float p[4][3] = {{0.f, 0.f, 0.f}, {0.f, 0.f, 0.f}, {0.f, 0.f, 0.f}, {0.f, 0.f, 0.f}};
#pragma unroll
        for (int ct = 0; ct < 16; ++ct) {
            int col = ct * 16 + r;
            float bv = b1s[col];
            float w0 = w2s[col], w1 = w2s[256 + col], w2v = w2s[512 + col];
#pragma unroll
            for (int reg = 0; reg < 4; ++reg) {
                float h4 = fmaxf(acc[ct][reg] + bv, 0.f);
                p[reg][0] += h4 * w0;
                p[reg][1] += h4 * w1;
                p[reg][2] += h4 * w2v;
            }
        }
#pragma unroll
        for (int m = 1; m < 16; m <<= 1)
#pragma unroll
            for (int reg = 0; reg < 4; ++reg) {
                p[reg][0] += __shfl_xor(p[reg][0], m);
                p[reg][1] += __shfl_xor(p[reg][1], m);
                p[reg][2] += __shfl_xor(p[reg][2], m);
            }
        if (r == 0) {
#pragma unroll
            for (int reg = 0; reg < 4; ++reg) {
                int row = (tile << 4) + half * 4 + reg;
                out[(size_t)row * 3 + 0] = p[reg][0] + c0;
                out[(size_t)row * 3 + 1] = p[reg][1] + c1;
                out[(size_t)row * 3 + 2] = p[reg][2] + c2;
            }
        }
    }
}

extern "C" void kernel_launch(void* const* d_in, const int* in_sizes, int n_in,
                              void* d_out, int out_size, void* d_ws, size_t ws_size,
                              hipStream_t stream) {
    const float* x   = (const float*)d_in[0];
    const int*   ei0 = (const int*)d_in[1];
    const int*   ei1 = (const int*)d_in[2];
    const float* Wl1 = (const float*)d_in[3];
    const float* bl1 = (const float*)d_in[4];
    const float* Wr1 = (const float*)d_in[5];
    const float* Wl2 = (const float*)d_in[6];
    const float* bl2 = (const float*)d_in[7];
    const float* Wr2 = (const float*)d_in[8];
    const float* Wsk = (const float*)d_in[9];
    const float* bsk = (const float*)d_in[10];
    const float* W1  = (const float*)d_in[11];
    const float* b1  = (const float*)d_in[12];
    const float* W2  = (const float*)d_in[13];
    const float* b2  = (const float*)d_in[14];
    float* out = (float*)d_out;

    const int N  = in_sizes[0] / DD;   // 50000
    const int E0 = in_sizes[1] / 2;    // 800000
    const int E1 = in_sizes[2] / 2;
    const int H  = in_sizes[12];       // 256

    const int* src0 = ei0;      const int* dst0 = ei0 + E0;
    const int* src1 = ei1;      const int* dst1 = ei1 + E1;

    const int nb   = (N + 255) >> SB;                  // 196 buckets
    const int Emax = (E0 > E1) ? E0 : E1;
    const int P    = (Emax + CH - 1) / CH;             // 196 partitions

    // workspace carve (256B aligned)
    char* wp = (char*)d_ws;
    auto carve = [&](size_t bytes) { char* p = wp; wp += (bytes + 255) & ~(size_t)255; return p; };
    u16* G1   = (u16*)carve((size_t)3 * N * DD * 2);   // planes: G1L | G1M | G1R
    u16* G2   = (u16*)carve((size_t)2 * N * DD * 2);   // planes: G2L | G2R
    u16* h1h  = (u16*)carve((size_t)N * DD * 2);
    u16* h3h  = (u16*)carve((size_t)N * DD * 2);
    u16* wc1  = (u16*)carve((size_t)384 * DD * 2);     // [Wl1;Wr1;Ws]
    u16* wc2  = (u16*)carve((size_t)256 * DD * 2);     // [Wl2;Wr2]
    u16* w1h  = (u16*)carve((size_t)H * DD * 2);
    int* rp0  = (int*)carve((size_t)(N + 1) * 4);
    int* rp1  = (int*)carve((size_t)(N + 1) * 4);
    u16* csr0 = (u16*)carve((size_t)E0 * 2);
    u16* csr1 = (u16*)carve((size_t)E1 * 2);
    unsigned* binned0 = (unsigned*)carve((size_t)E0 * 4);
    unsigned* binned1 = (unsigned*)carve((size_t)E1 * 4);
    int* hist1_0 = (int*)carve((size_t)nb * P * 4);
    int* hist1_1 = (int*)carve((size_t)nb * P * 4);
    int* bsum0 = (int*)carve((size_t)nb * 4);
    int* bsum1 = (int*)carve((size_t)nb * 4);
    int* bb0 = (int*)carve((size_t)(nb + 1) * 4);
    int* bb1 = (int*)carve((size_t)(nb + 1) * 4);

    const u16* G1L = G1;
    const u16* G1M = G1 + (size_t)N * DD;
    const u16* G1R = G1 + (size_t)2 * N * DD;
    const u16* G2L = G2;
    const u16* G2R = G2 + (size_t)N * DD;

    // weight cast into concat slots
    CastJobs jb;
    const float* srcs[6] = {Wl1, Wr1, Wsk, Wl2, Wr2, W1};
    u16* dsts[6] = {wc1, wc1 + 128 * DD, wc1 + 256 * DD, wc2, wc2 + 128 * DD, w1h};
    int  cnts[6] = {DD * DD, DD * DD, DD * DD, DD * DD, DD * DD, H * DD};
    int q = 0;
    for (int i = 0; i < 6; ++i) {
        jb.src[i] = (const float4*)srcs[i];
        jb.dst[i] = (uint2*)dsts[i];
        jb.qstart[i] = q;
        q += cnts[i] / 4;
    }
    jb.qstart[6] = q;

    const int gAgg = (N * 64 + 255) / 256;   // one wave per node

    cast_kernel<<<(q + 255) / 256, 256, 0, stream>>>(jb);
    hist1_kernel<<<dim3(P, 2), 256, 0, stream>>>(dst0, hist1_0, dst1, hist1_1, E0, E1, nb, P);
    rowsum_kernel<<<dim3(nb, 2), 256, 0, stream>>>(hist1_0, bsum0, hist1_1, bsum1, P);
    bscan_kernel<<<2, 256, 0, stream>>>(bsum0, bb0, rp0, E0, bsum1, bb1, rp1, E1, nb, N);
    offs_kernel<<<dim3(nb, 2), 256, 0, stream>>>(hist1_0, bb0, hist1_1, bb1, P);
    scatter1_kernel<<<dim3(P, 2), 256, 0, stream>>>(src0, dst0, hist1_0, binned0,
                                                    src1, dst1, hist1_1, binned1, E0, E1, nb, P);
    place_kernel<<<dim3(nb, 2), 256, 0, stream>>>(binned0, bb0, rp0, csr0,
                                                  binned1, bb1, rp1, csr1, N, nb);

    // G1 planes = x @ [Wl1;Wr1;Ws].T  (fp32 A direct-to-register)
    mfma_gemm<true><<<dim3(320, 3), 256, 0, stream>>>(x, wc1, G1, N);
    // h1 = mean_nbr0(G1L) + G1M + bl1
    agg1_kernel<<<gAgg, 256, 0, stream>>>((const unsigned*)G1L, (const unsigned*)G1M,
                                          csr0, rp0, bl1, (unsigned*)h1h, N);
    // G2 planes = h1 @ [Wl2;Wr2].T
    mfma_gemm<false><<<dim3(320, 2), 256, 0, stream>>>(h1h, wc2, G2, N);
    // h3 = mean_nbr1(G2L) + G2R + G1R + bl2 + bs
    agg2_kernel<<<gAgg, 256, 0, stream>>>((const unsigned*)G2L, (const unsigned*)G2R,
                                          (const unsigned*)G1R, csr1, rp1, bl2, bsk,
                                          (unsigned*)h3h, N);
    // out = relu(h3@W1.T + b1) @ W2.T + b2   (h4 in registers)
    gemm_out_kernel<<<512, 256, 0, stream>>>(h3h, w1h, b1, W2, b2, out, N);
}